// Round 15
// baseline (2602.944 us; speedup 1.0000x reference)
//
#include <hip/hip_runtime.h>
#include <hip/hip_bf16.h>
#include <stdint.h>

// Problem sizes (fixed by the reference)
#define IN_F  4096
#define OUT_F 4096
#define NROWS 16384
#define NT    (IN_F / 64)   // 64 K-tiles of BK=64

typedef unsigned short u16;
typedef unsigned int u32;
typedef unsigned long long u64;
typedef __bf16 bf16x8 __attribute__((ext_vector_type(8)));
typedef float  f32x4  __attribute__((ext_vector_type(4)));
typedef u16    u16x8  __attribute__((ext_vector_type(8)));

#define BAR()   asm volatile("s_barrier" ::: "memory")
#define VM8()   asm volatile("s_waitcnt vmcnt(8)" ::: "memory")
#define VM4()   asm volatile("s_waitcnt vmcnt(4)" ::: "memory")
#define VM0()   asm volatile("s_waitcnt vmcnt(0)" ::: "memory")

// fp32 -> bf16, round-to-nearest-even (finite inputs only)
__device__ __forceinline__ u16 f2bf(float x) {
    union { float f; uint32_t u; } c; c.f = x;
    uint32_t u = c.u;
    return (u16)((u + 0x7FFFu + ((u >> 16) & 1u)) >> 16);
}

// async global->LDS, 16B per lane. LDS dest = wave-uniform base + lane*16.
__device__ __forceinline__ void gload_lds16(const void* g, void* l) {
    __builtin_amdgcn_global_load_lds(
        (const __attribute__((address_space(1))) void*)g,
        (__attribute__((address_space(3))) void*)l, 16, 0, 0);
}

__device__ __forceinline__ u16 sgn_bf16(float v) {
    return v > 0.f ? 0x3F80 : (v < 0.f ? 0xBF80 : 0);
}

// --- Prep 1 (fast path): per-row alpha = mean(|W|) AND bit-packed signs,
// layout Wbits[kword][row] (kword == K-tile index since BK=64). Bitmap = 2MB,
// L2-resident in every XCD (r4 verified: FETCH 1.16GB -> ~100MB compulsory).
__global__ void prep_wbits_kernel(const float* __restrict__ W,
                                  float* __restrict__ alpha,
                                  u64* __restrict__ Wbits) {
    const int row = blockIdx.x;                       // 0..OUT_F-1
    const int wave = threadIdx.x >> 6, lane = threadIdx.x & 63;
    const float* wr = W + (size_t)row * IN_F;
    float s = 0.f;
#pragma unroll 4
    for (int it = 0; it < 16; ++it) {
        const int kword = it * 4 + wave;              // 64 words per row
        float v = __builtin_nontemporal_load(wr + kword * 64 + lane);
        s += fabsf(v);
        u64 m = __ballot(v > 0.f);                    // 64-bit wave mask
        if (lane == 0) Wbits[(size_t)kword * OUT_F + row] = m;
    }
    for (int off = 32; off > 0; off >>= 1) s += __shfl_down(s, off);
    __shared__ float red[4];
    if (lane == 0) red[wave] = s;
    __syncthreads();
    if (threadIdx.x == 0)
        alpha[row] = (red[0] + red[1] + red[2] + red[3]) * (1.0f / IN_F);
}

// --- Prep 2: x fp32 -> bf16 (RNE), chunk-swizzled for T2 (c8 ^= row&7) ---
__global__ void convx_kernel(const float* __restrict__ X, u16* __restrict__ O,
                             int swz) {
    const size_t idx = (size_t)blockIdx.x * 256 + threadIdx.x; // 16B out chunk
    const int row = (int)(idx >> 9);                 // 512 chunks per row
    const int q = (int)idx & 511;
    const int g = q >> 3, c8 = q & 7;
    const int c8s = swz ? (c8 ^ (row & 7)) : c8;
    const f32x4* src = reinterpret_cast<const f32x4*>(
        X + (size_t)row * IN_F + g * 64 + c8s * 8);
    f32x4 a = __builtin_nontemporal_load(src);
    f32x4 b = __builtin_nontemporal_load(src + 1);
    u16x8 r;
    r[0] = f2bf(a[0]); r[1] = f2bf(a[1]); r[2] = f2bf(a[2]); r[3] = f2bf(a[3]);
    r[4] = f2bf(b[0]); r[5] = f2bf(b[1]); r[6] = f2bf(b[2]); r[7] = f2bf(b[3]);
    reinterpret_cast<u16x8*>(O)[idx] = r;
}

// ============================================================================
// Round 15: r14 structure + THREE co-resident WGs per CU (launch_bounds 256,3).
// r14 verified: counted boundary works, 0 conflicts, no spill -- but MfmaUtil
// stuck at 53% with matrix-pipe idle 47%. Cycle audit: 32768 MFMA/SIMD x
// 19.4cyc = 636K = 0.53 x measured 1.14M cycles -> the idle is phase stall:
// with only 2 waves/SIMD (1 per WG), whenever both waves sit in their
// ds_read/expand phase the matrix pipe drains. Third wave/SIMD raises
// expected coverage (1-p^3 vs 1-p^2). Cost check: LDS 48KB x 3 = 144KB
// <= 160KB; VGPR 128 <= 170 cap @3 waves/SIMD. Per-XCD A footprint 4->6MB
// (slightly over L2, L3 absorbs -- FETCH may tick up; harmless).
// Everything else byte-identical to r14 (ledger: bits(t+1) before A(t+2),
// boundary VM8 drains exactly A(t+1); tail VM0; one BAR/tile).
// ============================================================================
__global__ __launch_bounds__(256, 3) void gemm8_kernel(
    const u16* __restrict__ Xbf, const u64* __restrict__ Wbits,
    const float* __restrict__ alpha, const float* __restrict__ bias,
    float* __restrict__ Y) {
    __shared__ u16 Alds[3][8192];   // 48KB: A triple buffer [128 rows][64 k]

    const int tid  = threadIdx.x;
    const int lane = tid & 63, wn = tid >> 6;     // 4 waves, all N-split
    const int lrow = lane & 15;

    const int wg = blockIdx.x;                    // 2048 WGs
    const int i  = wg >> 3;                       // 0..255 within XCD
    const int m0 = (((wg & 7) << 4) | (i >> 4)) << 7;   // (xcd*16+mloc)*128
    const int n0 = (i & 15) << 8;                 // n-tile * 256

    // T2 swizzled A ds_read k-offsets (u16 units) -- r11's exact pattern
    const int q0 = ((lane >> 4) << 3) ^ ((lrow & 7) << 3);
    const int q1 = q0 ^ 32;
    const int sh = (lane >> 4) << 3;              // bit offset within 32-k half

    f32x4 acc[8][4];
#pragma unroll
    for (int a = 0; a < 8; ++a)
#pragma unroll
        for (int b = 0; b < 4; ++b) acc[a][b] = (f32x4){0.f, 0.f, 0.f, 0.f};

    // stage one 64-row half of the 128-row A K-tile (2 gload_lds16 / thread)
    auto stageA = [&](int th, int half, u16* buf) {
        if (th >= NT) return;
#pragma unroll
        for (int j = 0; j < 2; ++j) {
            const int c = half * 512 + j * 256 + tid;     // 16B chunk idx
            const int row = c >> 3, c8 = c & 7;
            gload_lds16(Xbf + (size_t)(m0 + row) * IN_F + th * 64 + c8 * 8,
                        buf + c * 8);
        }
    };

    u64 wcur[4];
    auto loadbits = [&](int th) {
        if (th >= NT) return;
#pragma unroll
        for (int nf = 0; nf < 4; ++nf)
            wcur[nf] = Wbits[(size_t)th * OUT_F + n0 + wn * 64 + nf * 16 + lrow];
    };

    // expand lane's B-frag pair (kk=0,1) for one nf from its 64 sign bits.
    // bit=1 -> +1 (0x3F80), bit=0 -> -1 (0xBF80). r4/r11-verified math.
    auto expand_pair = [&](u64 w, bf16x8* dst) {
        u64 t64 = w >> sh;
        unsigned nb0 = ~(unsigned)t64;            // kk=0 byte at [7:0]
        unsigned nb1 = ~(unsigned)(t64 >> 32);    // kk=1 byte at [7:0]
        union { unsigned u[4]; bf16x8 v; } r0, r1;
#pragma unroll
        for (int e = 0; e < 4; ++e) {
            unsigned s0 = nb0 >> (2 * e), s1 = nb1 >> (2 * e);
            r0.u[e] = 0x3F803F80u | ((s0 & 1u) << 15) | ((s0 & 2u) << 30);
            r1.u[e] = 0x3F803F80u | ((s1 & 1u) << 15) | ((s1 & 2u) << 30);
        }
        dst[0] = r0.v; dst[1] = r1.v;
    };

    // rotating A-buffer pointers: pa0 = A(t), pa1 = A(t+1), pa2 = stage target
    u16* pa0 = &Alds[0][0];
    u16* pa1 = &Alds[1][0];
    u16* pa2 = &Alds[2][0];

    // ---- prologue: bits(0) FIRST, then A(0), A(1) -> VM4 drains bits0+A(0),
    // leaves A(1)x4 in flight (steady-state invariant) ----
    loadbits(0);
    stageA(0, 0, pa0); stageA(0, 1, pa0);
    stageA(1, 0, pa1); stageA(1, 1, pa1);
    VM4(); BAR();

    for (int t = 0; t < NT; ++t) {
        const u16* Ar = pa0 + lrow * 64;
        bf16x8 af0[8], af1[8];
#pragma unroll
        for (int mm = 0; mm < 8; ++mm) {          // rows mm*16 + lrow
            af0[mm] = *reinterpret_cast<const bf16x8*>(Ar + mm * 1024 + q0);
            af1[mm] = *reinterpret_cast<const bf16x8*>(Ar + mm * 1024 + q1);
        }

        bf16x8 bP[2], bQ[2];
        // --- nn=0 (expand auto-waits wcur -> drains up to bits(t), leaves
        // A(t+1) in flight: bits(t) was issued BEFORE stageA(t+1) at t-1) ---
        expand_pair(wcur[0], bP);
        __builtin_amdgcn_s_setprio(1);
#pragma unroll
        for (int mm = 0; mm < 8; ++mm) {
            acc[mm][0] = __builtin_amdgcn_mfma_f32_16x16x32_bf16(af0[mm], bP[0], acc[mm][0], 0, 0, 0);
            acc[mm][0] = __builtin_amdgcn_mfma_f32_16x16x32_bf16(af1[mm], bP[1], acc[mm][0], 0, 0, 0);
        }
        __builtin_amdgcn_s_setprio(0);
        // --- nn=1 ---
        expand_pair(wcur[1], bQ);
        __builtin_amdgcn_s_setprio(1);
#pragma unroll
        for (int mm = 0; mm < 8; ++mm) {
            acc[mm][1] = __builtin_amdgcn_mfma_f32_16x16x32_bf16(af0[mm], bQ[0], acc[mm][1], 0, 0, 0);
            acc[mm][1] = __builtin_amdgcn_mfma_f32_16x16x32_bf16(af1[mm], bQ[1], acc[mm][1], 0, 0, 0);
        }
        __builtin_amdgcn_s_setprio(0);
        // --- nn=2 ---
        expand_pair(wcur[2], bP);
        __builtin_amdgcn_s_setprio(1);
#pragma unroll
        for (int mm = 0; mm < 8; ++mm) {
            acc[mm][2] = __builtin_amdgcn_mfma_f32_16x16x32_bf16(af0[mm], bP[0], acc[mm][2], 0, 0, 0);
            acc[mm][2] = __builtin_amdgcn_mfma_f32_16x16x32_bf16(af1[mm], bP[1], acc[mm][2], 0, 0, 0);
        }
        __builtin_amdgcn_s_setprio(0);
        // --- nn=3: expand first (reads wcur[3]), THEN reload wcur=bits(t+1),
        // THEN stageA(t+2) -- ledger order bits-before-A; issue hides under
        // the nn=3 MFMA cluster ---
        expand_pair(wcur[3], bQ);
        loadbits(t + 1);
        stageA(t + 2, 0, pa2); stageA(t + 2, 1, pa2);
        __builtin_amdgcn_s_setprio(1);
#pragma unroll
        for (int mm = 0; mm < 8; ++mm) {
            acc[mm][3] = __builtin_amdgcn_mfma_f32_16x16x32_bf16(af0[mm], bQ[0], acc[mm][3], 0, 0, 0);
            acc[mm][3] = __builtin_amdgcn_mfma_f32_16x16x32_bf16(af1[mm], bQ[1], acc[mm][3], 0, 0, 0);
        }
        __builtin_amdgcn_s_setprio(0);

        // counted boundary: drain A(t+1) only (oldest 4 of 12); tail drains all
        if (t >= NT - 2) { VM0(); } else { VM8(); }
        BAR();

        u16* tp = pa0; pa0 = pa1; pa1 = pa2; pa2 = tp;
    }

    // epilogue: y = acc*alpha[col] + bias[col]; C/D: col=lane&15, row=(lane>>4)*4+r
#pragma unroll
    for (int nf = 0; nf < 4; ++nf) {
        const int col = n0 + wn * 64 + nf * 16 + lrow;
        const float al = alpha[col], bi = bias[col];
#pragma unroll
        for (int mf = 0; mf < 8; ++mf) {
            const int rbase = m0 + mf * 16 + ((lane >> 4) << 2);
#pragma unroll
            for (int r = 0; r < 4; ++r)
                __builtin_nontemporal_store(acc[mf][nf][r] * al + bi,
                    &Y[(size_t)(rbase + r) * OUT_F + col]);
        }
    }
}

// ============================================================================
// Fallback (small workspace): round-1 128x128 kernel, A reg-staged from fp32,
// bf16 Wsign unswizzled. Verified correct in round 1.
// ============================================================================
__global__ void prep_w_kernel(const float* __restrict__ W,
                              float* __restrict__ alpha,
                              u16* __restrict__ S) {
    const int row = blockIdx.x;
    const float* wr = W + (size_t)row * IN_F;
    float s = 0.f;
    for (int c = threadIdx.x; c < 512; c += 256) {
        const f32x4* src = reinterpret_cast<const f32x4*>(wr + c * 8);
        f32x4 v0 = __builtin_nontemporal_load(src);
        f32x4 v1 = __builtin_nontemporal_load(src + 1);
        s += fabsf(v0[0]) + fabsf(v0[1]) + fabsf(v0[2]) + fabsf(v0[3])
           + fabsf(v1[0]) + fabsf(v1[1]) + fabsf(v1[2]) + fabsf(v1[3]);
        u16x8 r;
        r[0] = sgn_bf16(v0[0]); r[1] = sgn_bf16(v0[1]);
        r[2] = sgn_bf16(v0[2]); r[3] = sgn_bf16(v0[3]);
        r[4] = sgn_bf16(v1[0]); r[5] = sgn_bf16(v1[1]);
        r[6] = sgn_bf16(v1[2]); r[7] = sgn_bf16(v1[3]);
        *reinterpret_cast<u16x8*>(S + (size_t)row * IN_F + c * 8) = r;
    }
    for (int off = 32; off > 0; off >>= 1) s += __shfl_down(s, off);
    __shared__ float red[4];
    const int wave = threadIdx.x >> 6, lane = threadIdx.x & 63;
    if (lane == 0) red[wave] = s;
    __syncthreads();
    if (threadIdx.x == 0)
        alpha[row] = (red[0] + red[1] + red[2] + red[3]) * (1.0f / IN_F);
}

__global__ __launch_bounds__(256) void gemm_fallback(
    const float* __restrict__ X, const u16* __restrict__ Wsign,
    const float* __restrict__ alpha, const float* __restrict__ bias,
    float* __restrict__ Y) {
    __shared__ u16 Axl[128 * 64];
    __shared__ u16 Bxl[128 * 64];

    const int tid = threadIdx.x;
    const int n0 = blockIdx.x * 128;
    const int m0 = blockIdx.y * 128;
    const int wave = tid >> 6, lane = tid & 63;
    const int wm = wave >> 1, wn = wave & 1;
    const int lrow = lane & 15;
    const int lk8 = (lane >> 4) * 8;

    f32x4 acc[4][4];
#pragma unroll
    for (int a = 0; a < 4; ++a)
#pragma unroll
        for (int b = 0; b < 4; ++b) acc[a][b] = (f32x4){0.f, 0.f, 0.f, 0.f};

    for (int kt = 0; kt < IN_F; kt += 64) {
#pragma unroll
        for (int j = 0; j < 4; ++j) {
            const int idx = j * 256 + tid;
            const int row = idx >> 3, c8 = idx & 7;
            gload_lds16(Wsign + (size_t)(n0 + row) * IN_F + kt + c8 * 8,
                        &Bxl[idx * 8]);
        }
#pragma unroll
        for (int j = 0; j < 4; ++j) {
            const int idx = j * 256 + tid;
            const int row = idx >> 3, c8 = idx & 7;
            const float* src = X + (size_t)(m0 + row) * IN_F + kt + c8 * 8;
            float4 v0 = *reinterpret_cast<const float4*>(src);
            float4 v1 = *reinterpret_cast<const float4*>(src + 4);
            u16x8 r;
            r[0] = f2bf(v0.x); r[1] = f2bf(v0.y); r[2] = f2bf(v0.z); r[3] = f2bf(v0.w);
            r[4] = f2bf(v1.x); r[5] = f2bf(v1.y); r[6] = f2bf(v1.z); r[7] = f2bf(v1.w);
            *reinterpret_cast<u16x8*>(&Axl[idx * 8]) = r;
        }
        __syncthreads();
#pragma unroll
        for (int kk = 0; kk < 2; ++kk) {
            bf16x8 af[4], bfv[4];
#pragma unroll
            for (int mf = 0; mf < 4; ++mf)
                af[mf] = *reinterpret_cast<const bf16x8*>(
                    &Axl[(wm * 64 + mf * 16 + lrow) * 64 + kk * 32 + lk8]);
#pragma unroll
            for (int nf = 0; nf < 4; ++nf)
                bfv[nf] = *reinterpret_cast<const bf16x8*>(
                    &Bxl[(wn * 64 + nf * 16 + lrow) * 64 + kk * 32 + lk8]);
#pragma unroll
            for (int mf = 0; mf < 4; ++mf)
#pragma unroll
                for (int nf = 0; nf < 4; ++nf)
                    acc[mf][nf] = __builtin_amdgcn_mfma_f32_16x16x32_bf16(
                        af[mf], bfv[nf], acc[mf][nf], 0, 0, 0);
        }
        __syncthreads();
    }
#pragma unroll
    for (int nf = 0; nf < 4; ++nf) {
        const int col = n0 + wn * 64 + nf * 16 + lrow;
        const float al = alpha[col], bi = bias[col];
#pragma unroll
        for (int mf = 0; mf < 4; ++mf) {
            const int rbase = m0 + wm * 64 + mf * 16 + (lane >> 4) * 4;
#pragma unroll
            for (int r = 0; r < 4; ++r)
                __builtin_nontemporal_store(acc[mf][nf][r] * al + bi,
                    &Y[(size_t)(rbase + r) * OUT_F + col]);
        }
    }
}

extern "C" void kernel_launch(void* const* d_in, const int* in_sizes, int n_in,
                              void* d_out, int out_size, void* d_ws, size_t ws_size,
                              hipStream_t stream) {
    const float* X    = (const float*)d_in[0];
    const float* W    = (const float*)d_in[1];
    const float* bias = (const float*)d_in[2];
    float* Y = (float*)d_out;

    char* ws = (char*)d_ws;
    float* alpha = (float*)ws;                               // 16 KB
    const size_t WBITS_OFF = 16384;
    const size_t XBF_OFF   = WBITS_OFF + (size_t)OUT_F * (IN_F / 8); // +2 MB
    const size_t need_fast = XBF_OFF + (size_t)NROWS * IN_F * 2;     // +128 MB

    if (ws_size >= need_fast) {
        u64* Wbits = (u64*)(ws + WBITS_OFF);
        u16* Xbf   = (u16*)(ws + XBF_OFF);
        prep_wbits_kernel<<<OUT_F, 256, 0, stream>>>(W, alpha, Wbits);
        convx_kernel<<<(size_t)NROWS * IN_F / 8 / 256, 256, 0, stream>>>(X, Xbf, 1);
        gemm8_kernel<<<dim3(2048), 256, 0, stream>>>(Xbf, Wbits, alpha, bias, Y);
    } else {
        u16* Wsign = (u16*)(ws + 16384);
        prep_w_kernel<<<OUT_F, 256, 0, stream>>>(W, alpha, Wsign);
        dim3 grid(OUT_F / 128, NROWS / 128);
        gemm_fallback<<<grid, 256, 0, stream>>>(X, Wsign, alpha, bias, Y);
    }
}

// Round 16
// 514.092 us; speedup vs baseline: 5.0632x; 5.0632x over previous
//
#include <hip/hip_runtime.h>
#include <hip/hip_bf16.h>
#include <stdint.h>

// Problem sizes (fixed by the reference)
#define IN_F  4096
#define OUT_F 4096
#define NROWS 16384
#define NT    (IN_F / 64)   // 64 K-tiles of BK=64

typedef unsigned short u16;
typedef unsigned int u32;
typedef unsigned long long u64;
typedef __bf16 bf16x8 __attribute__((ext_vector_type(8)));
typedef float  f32x4  __attribute__((ext_vector_type(4)));
typedef u16    u16x8  __attribute__((ext_vector_type(8)));

#define BAR()   asm volatile("s_barrier" ::: "memory")
#define VM8()   asm volatile("s_waitcnt vmcnt(8)" ::: "memory")
#define VM4()   asm volatile("s_waitcnt vmcnt(4)" ::: "memory")
#define VM0()   asm volatile("s_waitcnt vmcnt(0)" ::: "memory")

// fp32 -> bf16, round-to-nearest-even (finite inputs only)
__device__ __forceinline__ u16 f2bf(float x) {
    union { float f; uint32_t u; } c; c.f = x;
    uint32_t u = c.u;
    return (u16)((u + 0x7FFFu + ((u >> 16) & 1u)) >> 16);
}

// async global->LDS, 16B per lane. LDS dest = wave-uniform base + lane*16.
__device__ __forceinline__ void gload_lds16(const void* g, void* l) {
    __builtin_amdgcn_global_load_lds(
        (const __attribute__((address_space(1))) void*)g,
        (__attribute__((address_space(3))) void*)l, 16, 0, 0);
}

__device__ __forceinline__ u16 sgn_bf16(float v) {
    return v > 0.f ? 0x3F80 : (v < 0.f ? 0xBF80 : 0);
}

// --- Prep 1 (fast path): per-row alpha = mean(|W|) AND bit-packed signs,
// layout Wbits[kword][row]. Bitmap = 2MB, L2-resident in every XCD.
__global__ void prep_wbits_kernel(const float* __restrict__ W,
                                  float* __restrict__ alpha,
                                  u64* __restrict__ Wbits) {
    const int row = blockIdx.x;                       // 0..OUT_F-1
    const int wave = threadIdx.x >> 6, lane = threadIdx.x & 63;
    const float* wr = W + (size_t)row * IN_F;
    float s = 0.f;
#pragma unroll 4
    for (int it = 0; it < 16; ++it) {
        const int kword = it * 4 + wave;              // 64 words per row
        float v = __builtin_nontemporal_load(wr + kword * 64 + lane);
        s += fabsf(v);
        u64 m = __ballot(v > 0.f);                    // 64-bit wave mask
        if (lane == 0) Wbits[(size_t)kword * OUT_F + row] = m;
    }
    for (int off = 32; off > 0; off >>= 1) s += __shfl_down(s, off);
    __shared__ float red[4];
    if (lane == 0) red[wave] = s;
    __syncthreads();
    if (threadIdx.x == 0)
        alpha[row] = (red[0] + red[1] + red[2] + red[3]) * (1.0f / IN_F);
}

// --- Prep 2: x fp32 -> bf16 (RNE), chunk-swizzled for T2 (c8 ^= row&7) ---
__global__ void convx_kernel(const float* __restrict__ X, u16* __restrict__ O,
                             int swz) {
    const size_t idx = (size_t)blockIdx.x * 256 + threadIdx.x; // 16B out chunk
    const int row = (int)(idx >> 9);                 // 512 chunks per row
    const int q = (int)idx & 511;
    const int g = q >> 3, c8 = q & 7;
    const int c8s = swz ? (c8 ^ (row & 7)) : c8;
    const f32x4* src = reinterpret_cast<const f32x4*>(
        X + (size_t)row * IN_F + g * 64 + c8s * 8);
    f32x4 a = __builtin_nontemporal_load(src);
    f32x4 b = __builtin_nontemporal_load(src + 1);
    u16x8 r;
    r[0] = f2bf(a[0]); r[1] = f2bf(a[1]); r[2] = f2bf(a[2]); r[3] = f2bf(a[3]);
    r[4] = f2bf(b[0]); r[5] = f2bf(b[1]); r[6] = f2bf(b[2]); r[7] = f2bf(b[3]);
    reinterpret_cast<u16x8*>(O)[idx] = r;
}

// ============================================================================
// Round 16: r14 EXACT structure (2 WGs/CU, proven best: 477us GEMM, 0
// conflicts, no spill, counted VM8 boundary) + K-PHASE STAGGER.
// r15 post-mortem: 3 waves/SIMD impossible -- acc(128 AGPR)+working > 170-reg
// cap -> VGPR clamped to 84, acc spilled (FETCH 3.8GB). 2 waves/SIMD is
// structural with a 128-reg accumulator. Reverted.
// r14 residual: 4473 cyc/tile/SIMD = ~1536 LDS-read burst + 2483 MFMA, near
// serial at CU level -- co-resident WGs start together, identical tiles ->
// barriers stay phase-ALIGNED all kernel: everyone ds_reads together (matrix
// idle) then MFMAs together (LDS idle). Fix: K-sum is commutative, so each WG
// starts its K-loop at phase = ((wg>>3)&3)*16, tile = (t+phase)&63. 75% of
// co-resident pairs get different phases -> one WG's LDS burst lands in the
// other's MFMA window. A-slab L2 residency unchanged (slab spans all K).
// Ledger: steady-state always-VM8 (boundary queue [A(t+1)x4, bits x4,
// A(t+2)x4]); wrap-staged tail tiles are written-never-read (harmless);
// VM0 before epilogue drains everything.
// ============================================================================
__global__ __launch_bounds__(256, 2) void gemm8_kernel(
    const u16* __restrict__ Xbf, const u64* __restrict__ Wbits,
    const float* __restrict__ alpha, const float* __restrict__ bias,
    float* __restrict__ Y) {
    __shared__ u16 Alds[3][8192];   // 48KB: A triple buffer [128 rows][64 k]

    const int tid  = threadIdx.x;
    const int lane = tid & 63, wn = tid >> 6;     // 4 waves, all N-split
    const int lrow = lane & 15;

    const int wg = blockIdx.x;                    // 2048 WGs
    const int i  = wg >> 3;                       // 0..255 within XCD
    const int m0 = (((wg & 7) << 4) | (i >> 4)) << 7;   // (xcd*16+mloc)*128
    const int n0 = (i & 15) << 8;                 // n-tile * 256
    const int phase = (i & 3) << 4;               // K-phase stagger 0/16/32/48

    // T2 swizzled A ds_read k-offsets (u16 units) -- r11's exact pattern
    const int q0 = ((lane >> 4) << 3) ^ ((lrow & 7) << 3);
    const int q1 = q0 ^ 32;
    const int sh = (lane >> 4) << 3;              // bit offset within 32-k half

    f32x4 acc[8][4];
#pragma unroll
    for (int a = 0; a < 8; ++a)
#pragma unroll
        for (int b = 0; b < 4; ++b) acc[a][b] = (f32x4){0.f, 0.f, 0.f, 0.f};

    // stage one 64-row half of the 128-row A K-tile th (masked, may wrap)
    auto stageA = [&](int th, int half, u16* buf) {
        const int tk = th & 63;
#pragma unroll
        for (int j = 0; j < 2; ++j) {
            const int c = half * 512 + j * 256 + tid;     // 16B chunk idx
            const int row = c >> 3, c8 = c & 7;
            gload_lds16(Xbf + (size_t)(m0 + row) * IN_F + tk * 64 + c8 * 8,
                        buf + c * 8);
        }
    };

    u64 wcur[4];
    auto loadbits = [&](int th) {
        const int tk = th & 63;
#pragma unroll
        for (int nf = 0; nf < 4; ++nf)
            wcur[nf] = Wbits[(size_t)tk * OUT_F + n0 + wn * 64 + nf * 16 + lrow];
    };

    // expand lane's B-frag pair (kk=0,1) for one nf from its 64 sign bits.
    // bit=1 -> +1 (0x3F80), bit=0 -> -1 (0xBF80). r4/r11-verified math.
    auto expand_pair = [&](u64 w, bf16x8* dst) {
        u64 t64 = w >> sh;
        unsigned nb0 = ~(unsigned)t64;            // kk=0 byte at [7:0]
        unsigned nb1 = ~(unsigned)(t64 >> 32);    // kk=1 byte at [7:0]
        union { unsigned u[4]; bf16x8 v; } r0, r1;
#pragma unroll
        for (int e = 0; e < 4; ++e) {
            unsigned s0 = nb0 >> (2 * e), s1 = nb1 >> (2 * e);
            r0.u[e] = 0x3F803F80u | ((s0 & 1u) << 15) | ((s0 & 2u) << 30);
            r1.u[e] = 0x3F803F80u | ((s1 & 1u) << 15) | ((s1 & 2u) << 30);
        }
        dst[0] = r0.v; dst[1] = r1.v;
    };

    // rotating A-buffer pointers: pa0 = A(t), pa1 = A(t+1), pa2 = stage target
    u16* pa0 = &Alds[0][0];
    u16* pa1 = &Alds[1][0];
    u16* pa2 = &Alds[2][0];

    // ---- prologue: bits(phase) FIRST, then A(phase), A(phase+1) ->
    // VM4 drains bits+A(0), leaves A(1)x4 in flight ----
    loadbits(phase);
    stageA(phase, 0, pa0); stageA(phase, 1, pa0);
    stageA(phase + 1, 0, pa1); stageA(phase + 1, 1, pa1);
    VM4(); BAR();

    for (int t = 0; t < NT; ++t) {
        const u16* Ar = pa0 + lrow * 64;
        bf16x8 af0[8], af1[8];
#pragma unroll
        for (int mm = 0; mm < 8; ++mm) {          // rows mm*16 + lrow
            af0[mm] = *reinterpret_cast<const bf16x8*>(Ar + mm * 1024 + q0);
            af1[mm] = *reinterpret_cast<const bf16x8*>(Ar + mm * 1024 + q1);
        }

        bf16x8 bP[2], bQ[2];
        // --- nn=0 (expand auto-waits wcur -> drains up to bits(t), leaves
        // A(t+1) in flight: bits(t) was issued BEFORE stageA(t+1) at t-1) ---
        expand_pair(wcur[0], bP);
        __builtin_amdgcn_s_setprio(1);
#pragma unroll
        for (int mm = 0; mm < 8; ++mm) {
            acc[mm][0] = __builtin_amdgcn_mfma_f32_16x16x32_bf16(af0[mm], bP[0], acc[mm][0], 0, 0, 0);
            acc[mm][0] = __builtin_amdgcn_mfma_f32_16x16x32_bf16(af1[mm], bP[1], acc[mm][0], 0, 0, 0);
        }
        __builtin_amdgcn_s_setprio(0);
        // --- nn=1 ---
        expand_pair(wcur[1], bQ);
        __builtin_amdgcn_s_setprio(1);
#pragma unroll
        for (int mm = 0; mm < 8; ++mm) {
            acc[mm][1] = __builtin_amdgcn_mfma_f32_16x16x32_bf16(af0[mm], bQ[0], acc[mm][1], 0, 0, 0);
            acc[mm][1] = __builtin_amdgcn_mfma_f32_16x16x32_bf16(af1[mm], bQ[1], acc[mm][1], 0, 0, 0);
        }
        __builtin_amdgcn_s_setprio(0);
        // --- nn=2 ---
        expand_pair(wcur[2], bP);
        __builtin_amdgcn_s_setprio(1);
#pragma unroll
        for (int mm = 0; mm < 8; ++mm) {
            acc[mm][2] = __builtin_amdgcn_mfma_f32_16x16x32_bf16(af0[mm], bP[0], acc[mm][2], 0, 0, 0);
            acc[mm][2] = __builtin_amdgcn_mfma_f32_16x16x32_bf16(af1[mm], bP[1], acc[mm][2], 0, 0, 0);
        }
        __builtin_amdgcn_s_setprio(0);
        // --- nn=3: expand first (reads wcur[3]), THEN reload wcur=bits(t+1),
        // THEN stageA(t+2) -- ledger order bits-before-A; issue hides under
        // the nn=3 MFMA cluster ---
        expand_pair(wcur[3], bQ);
        loadbits(phase + t + 1);
        stageA(phase + t + 2, 0, pa2); stageA(phase + t + 2, 1, pa2);
        __builtin_amdgcn_s_setprio(1);
#pragma unroll
        for (int mm = 0; mm < 8; ++mm) {
            acc[mm][3] = __builtin_amdgcn_mfma_f32_16x16x32_bf16(af0[mm], bQ[0], acc[mm][3], 0, 0, 0);
            acc[mm][3] = __builtin_amdgcn_mfma_f32_16x16x32_bf16(af1[mm], bQ[1], acc[mm][3], 0, 0, 0);
        }
        __builtin_amdgcn_s_setprio(0);

        // counted boundary: drain A(t+1) only (oldest 4 of 12)
        if (t == NT - 1) { VM0(); } else { VM8(); }
        BAR();

        u16* tp = pa0; pa0 = pa1; pa1 = pa2; pa2 = tp;
    }

    // epilogue: y = acc*alpha[col] + bias[col]; C/D: col=lane&15, row=(lane>>4)*4+r
#pragma unroll
    for (int nf = 0; nf < 4; ++nf) {
        const int col = n0 + wn * 64 + nf * 16 + lrow;
        const float al = alpha[col], bi = bias[col];
#pragma unroll
        for (int mf = 0; mf < 8; ++mf) {
            const int rbase = m0 + mf * 16 + ((lane >> 4) << 2);
#pragma unroll
            for (int r = 0; r < 4; ++r)
                __builtin_nontemporal_store(acc[mf][nf][r] * al + bi,
                    &Y[(size_t)(rbase + r) * OUT_F + col]);
        }
    }
}

// ============================================================================
// Fallback (small workspace): round-1 128x128 kernel, A reg-staged from fp32,
// bf16 Wsign unswizzled. Verified correct in round 1.
// ============================================================================
__global__ void prep_w_kernel(const float* __restrict__ W,
                              float* __restrict__ alpha,
                              u16* __restrict__ S) {
    const int row = blockIdx.x;
    const float* wr = W + (size_t)row * IN_F;
    float s = 0.f;
    for (int c = threadIdx.x; c < 512; c += 256) {
        const f32x4* src = reinterpret_cast<const f32x4*>(wr + c * 8);
        f32x4 v0 = __builtin_nontemporal_load(src);
        f32x4 v1 = __builtin_nontemporal_load(src + 1);
        s += fabsf(v0[0]) + fabsf(v0[1]) + fabsf(v0[2]) + fabsf(v0[3])
           + fabsf(v1[0]) + fabsf(v1[1]) + fabsf(v1[2]) + fabsf(v1[3]);
        u16x8 r;
        r[0] = sgn_bf16(v0[0]); r[1] = sgn_bf16(v0[1]);
        r[2] = sgn_bf16(v0[2]); r[3] = sgn_bf16(v0[3]);
        r[4] = sgn_bf16(v1[0]); r[5] = sgn_bf16(v1[1]);
        r[6] = sgn_bf16(v1[2]); r[7] = sgn_bf16(v1[3]);
        *reinterpret_cast<u16x8*>(S + (size_t)row * IN_F + c * 8) = r;
    }
    for (int off = 32; off > 0; off >>= 1) s += __shfl_down(s, off);
    __shared__ float red[4];
    const int wave = threadIdx.x >> 6, lane = threadIdx.x & 63;
    if (lane == 0) red[wave] = s;
    __syncthreads();
    if (threadIdx.x == 0)
        alpha[row] = (red[0] + red[1] + red[2] + red[3]) * (1.0f / IN_F);
}

__global__ __launch_bounds__(256) void gemm_fallback(
    const float* __restrict__ X, const u16* __restrict__ Wsign,
    const float* __restrict__ alpha, const float* __restrict__ bias,
    float* __restrict__ Y) {
    __shared__ u16 Axl[128 * 64];
    __shared__ u16 Bxl[128 * 64];

    const int tid = threadIdx.x;
    const int n0 = blockIdx.x * 128;
    const int m0 = blockIdx.y * 128;
    const int wave = tid >> 6, lane = tid & 63;
    const int wm = wave >> 1, wn = wave & 1;
    const int lrow = lane & 15;
    const int lk8 = (lane >> 4) * 8;

    f32x4 acc[4][4];
#pragma unroll
    for (int a = 0; a < 4; ++a)
#pragma unroll
        for (int b = 0; b < 4; ++b) acc[a][b] = (f32x4){0.f, 0.f, 0.f, 0.f};

    for (int kt = 0; kt < IN_F; kt += 64) {
#pragma unroll
        for (int j = 0; j < 4; ++j) {
            const int idx = j * 256 + tid;
            const int row = idx >> 3, c8 = idx & 7;
            gload_lds16(Wsign + (size_t)(n0 + row) * IN_F + kt + c8 * 8,
                        &Bxl[idx * 8]);
        }
#pragma unroll
        for (int j = 0; j < 4; ++j) {
            const int idx = j * 256 + tid;
            const int row = idx >> 3, c8 = idx & 7;
            const float* src = X + (size_t)(m0 + row) * IN_F + kt + c8 * 8;
            float4 v0 = *reinterpret_cast<const float4*>(src);
            float4 v1 = *reinterpret_cast<const float4*>(src + 4);
            u16x8 r;
            r[0] = f2bf(v0.x); r[1] = f2bf(v0.y); r[2] = f2bf(v0.z); r[3] = f2bf(v0.w);
            r[4] = f2bf(v1.x); r[5] = f2bf(v1.y); r[6] = f2bf(v1.z); r[7] = f2bf(v1.w);
            *reinterpret_cast<u16x8*>(&Axl[idx * 8]) = r;
        }
        __syncthreads();
#pragma unroll
        for (int kk = 0; kk < 2; ++kk) {
            bf16x8 af[4], bfv[4];
#pragma unroll
            for (int mf = 0; mf < 4; ++mf)
                af[mf] = *reinterpret_cast<const bf16x8*>(
                    &Axl[(wm * 64 + mf * 16 + lrow) * 64 + kk * 32 + lk8]);
#pragma unroll
            for (int nf = 0; nf < 4; ++nf)
                bfv[nf] = *reinterpret_cast<const bf16x8*>(
                    &Bxl[(wn * 64 + nf * 16 + lrow) * 64 + kk * 32 + lk8]);
#pragma unroll
            for (int mf = 0; mf < 4; ++mf)
#pragma unroll
                for (int nf = 0; nf < 4; ++nf)
                    acc[mf][nf] = __builtin_amdgcn_mfma_f32_16x16x32_bf16(
                        af[mf], bfv[nf], acc[mf][nf], 0, 0, 0);
        }
        __syncthreads();
    }
#pragma unroll
    for (int nf = 0; nf < 4; ++nf) {
        const int col = n0 + wn * 64 + nf * 16 + lrow;
        const float al = alpha[col], bi = bias[col];
#pragma unroll
        for (int mf = 0; mf < 4; ++mf) {
            const int rbase = m0 + wm * 64 + mf * 16 + (lane >> 4) * 4;
#pragma unroll
            for (int r = 0; r < 4; ++r)
                __builtin_nontemporal_store(acc[mf][nf][r] * al + bi,
                    &Y[(size_t)(rbase + r) * OUT_F + col]);
        }
    }
}

extern "C" void kernel_launch(void* const* d_in, const int* in_sizes, int n_in,
                              void* d_out, int out_size, void* d_ws, size_t ws_size,
                              hipStream_t stream) {
    const float* X    = (const float*)d_in[0];
    const float* W    = (const float*)d_in[1];
    const float* bias = (const float*)d_in[2];
    float* Y = (float*)d_out;

    char* ws = (char*)d_ws;
    float* alpha = (float*)ws;                               // 16 KB
    const size_t WBITS_OFF = 16384;
    const size_t XBF_OFF   = WBITS_OFF + (size_t)OUT_F * (IN_F / 8); // +2 MB
    const size_t need_fast = XBF_OFF + (size_t)NROWS * IN_F * 2;     // +128 MB

    if (ws_size >= need_fast) {
        u64* Wbits = (u64*)(ws + WBITS_OFF);
        u16* Xbf   = (u16*)(ws + XBF_OFF);
        prep_wbits_kernel<<<OUT_F, 256, 0, stream>>>(W, alpha, Wbits);
        convx_kernel<<<(size_t)NROWS * IN_F / 8 / 256, 256, 0, stream>>>(X, Xbf, 1);
        gemm8_kernel<<<dim3(2048), 256, 0, stream>>>(Xbf, Wbits, alpha, bias, Y);
    } else {
        u16* Wsign = (u16*)(ws + 16384);
        prep_w_kernel<<<OUT_F, 256, 0, stream>>>(W, alpha, Wsign);
        dim3 grid(OUT_F / 128, NROWS / 128);
        gemm_fallback<<<grid, 256, 0, stream>>>(X, Wsign, alpha, bias, Y);
    }
}